// Round 8
// baseline (649.385 us; speedup 1.0000x reference)
//
#include <hip/hip_runtime.h>
#include <math.h>

#define H_  16
#define K_  64
#define D_  1024
#define M_  4096
#define S_  2048
#define B_  4
#define N_  8192      // S*B
#define HK_ 1024      // H*K

// Externals (inputs + output) fp32. ws intermediates bf16.
typedef __attribute__((ext_vector_type(8))) short bfrag;   // 8 bf16 = 4 VGPRs (MFMA A/B frag)
typedef __attribute__((ext_vector_type(4))) float f4;      // MFMA C/D frag

typedef __attribute__((address_space(1))) const void g_void;
typedef __attribute__((address_space(3))) void s_void;

__device__ __forceinline__ float bf2f(unsigned short u){
  union { unsigned int i; float f; } x; x.i = ((unsigned int)u) << 16; return x.f;
}
__device__ __forceinline__ unsigned short f2bf(float f){
  unsigned int u = __float_as_uint(f);
  return (unsigned short)((u + 0x7fffu + ((u >> 16) & 1u)) >> 16);   // RNE
}
__device__ __forceinline__ unsigned int pack2(float a, float b){
  return (unsigned int)f2bf(a) | ((unsigned int)f2bf(b) << 16);
}
// async global->LDS, 16B per lane, dest = wave-uniform base + lane*16
__device__ __forceinline__ void gload16(const void* g, void* l){
  __builtin_amdgcn_global_load_lds((g_void*)g, (s_void*)l, 16, 0, 0);
}

// ---------------------------------------------------------------------------
// fp32 -> bf16 cast, 4 elems/thread
// ---------------------------------------------------------------------------
__global__ __launch_bounds__(256) void castk(const float* __restrict__ in,
                                             unsigned short* __restrict__ out){
  int i = (blockIdx.x * 256 + threadIdx.x) * 4;
  float4 v = *(const float4*)(in + i);
  *(uint2*)(out + i) = make_uint2(pack2(v.x, v.y), pack2(v.z, v.w));
}

// ---------------------------------------------------------------------------
// merged cast of 4x 1Mx-elem weights (wq,wk,wv,wc) -> contiguous bf16.
// grid 4096, 1024 blocks per input.
// ---------------------------------------------------------------------------
__global__ __launch_bounds__(256) void castw4(
    const float* __restrict__ a, const float* __restrict__ b,
    const float* __restrict__ c, const float* __restrict__ d,
    unsigned short* __restrict__ out){
  const int blk = blockIdx.x;
  const int seg = blk >> 10;
  const float* src = (seg == 0) ? a : (seg == 1) ? b : (seg == 2) ? c : d;
  const int rel = ((blk & 1023) * 256 + threadIdx.x) * 4;
  float4 v = *(const float4*)(src + rel);
  *(uint2*)(out + (size_t)seg * 1048576 + rel) = make_uint2(pack2(v.x, v.y), pack2(v.z, v.w));
}

// ---------------------------------------------------------------------------
// mask * log2(e), fp32 -> fp32 (lets fattn use exp2 directly: 1 fma + 1 exp)
// ---------------------------------------------------------------------------
__global__ __launch_bounds__(256) void mscale(const float* __restrict__ in,
                                              float* __restrict__ out){
  int i = (blockIdx.x * 256 + threadIdx.x) * 4;
  float4 v = *(const float4*)(in + i);
  const float c = 1.44269504f;
  v.x *= c; v.y *= c; v.z *= c; v.w *= c;
  *(float4*)(out + i) = v;
}

// ---------------------------------------------------------------------------
// MFMA GEMM v5 (R7-proven): 128x128 tile, BK=32, 4 waves, triple-buffered
// counted-vmcnt + XCD-chunked block swizzle (T1). LDS 48 KB.
// EPI: 0 = merged-QKV head-major out (proj = n>>10); 1 = +fp32 res;
// 2 = +bias relu; 3 = +bias +bf16 res.
// ---------------------------------------------------------------------------
template<int EPI>
__global__ __launch_bounds__(256) void mgemm(
    const unsigned short* __restrict__ A, const unsigned short* __restrict__ W,
    const float* __restrict__ bias, const void* __restrict__ res,
    unsigned short* __restrict__ C, int Kdim, int Ncols)
{
  __shared__ unsigned short sA[3][4096];   // 128 rows x 32 k, triple-buffered
  __shared__ unsigned short sB[3][4096];
  const int tid  = threadIdx.x;
  const int wave = tid >> 6, ln = tid & 63;
  const int lr   = ln & 15, quad = ln >> 4;

  // XCD-chunked swizzle (T1): hardware assigns bid -> XCD bid%8; remap so
  // XCD k processes logical tiles [k*cpx, (k+1)*cpx) in x-fastest order.
  const int nwg = gridDim.x * gridDim.y;
  const int bid = blockIdx.x + gridDim.x * blockIdx.y;
  const int cpx = nwg >> 3;                // nwg % 8 == 0 for all our grids
  const int swz = (bid & 7) * cpx + (bid >> 3);
  const int bx  = swz % gridDim.x, by = swz / gridDim.x;

  const int m0   = by * 128, n0 = bx * 128;
  const int wr   = (wave >> 1) * 64, wc = (wave & 1) * 64;
  const int segr = ln >> 2, segc = (ln & 3) * 8;
  const int sg   = wave * 2;

  const unsigned short* A0 = A + (size_t)(m0 + sg*16      + segr) * Kdim + segc;
  const unsigned short* A1 = A + (size_t)(m0 + sg*16 + 16 + segr) * Kdim + segc;
  const unsigned short* W0 = W + (size_t)(n0 + sg*16      + segr) * Kdim + segc;
  const unsigned short* W1 = W + (size_t)(n0 + sg*16 + 16 + segr) * Kdim + segc;

  const f4 zero = {0.f, 0.f, 0.f, 0.f};
  f4 acc[4][4];
  #pragma unroll
  for (int i=0;i<4;i++)
    #pragma unroll
    for (int j=0;j<4;j++) acc[i][j] = zero;

  auto stage = [&](int buf, int k0){
    gload16(A0 + k0, &sA[buf][sg*512]);
    gload16(A1 + k0, &sA[buf][sg*512 + 512]);
    gload16(W0 + k0, &sB[buf][sg*512]);
    gload16(W1 + k0, &sB[buf][sg*512 + 512]);
  };

  stage(0, 0);
  if (32 < Kdim) stage(1, 32);
  int cur = 0;

  for (int k0 = 0; k0 < Kdim; k0 += 32){
    // need chunk k0 landed; chunk k0+32 (4 loads) may stay in flight
    if (k0 + 32 < Kdim) asm volatile("s_waitcnt vmcnt(4)" ::: "memory");
    else                asm volatile("s_waitcnt vmcnt(0)" ::: "memory");
    __builtin_amdgcn_s_barrier();
    int nxt = cur + 2; if (nxt >= 3) nxt -= 3;
    if (k0 + 64 < Kdim) stage(nxt, k0 + 64);   // 2 compute phases to land

    bfrag af[4], bf[4];
    #pragma unroll
    for (int i=0;i<4;i++) af[i] = *(const bfrag*)&sA[cur][(wr + i*16 + lr)*32 + quad*8];
    #pragma unroll
    for (int j=0;j<4;j++) bf[j] = *(const bfrag*)&sB[cur][(wc + j*16 + lr)*32 + quad*8];
    #pragma unroll
    for (int i=0;i<4;i++)
      #pragma unroll
      for (int j=0;j<4;j++)
        acc[i][j] = __builtin_amdgcn_mfma_f32_16x16x32_bf16(af[i], bf[j], acc[i][j], 0, 0, 0);
    cur = (cur + 1 == 3) ? 0 : cur + 1;
  }

  #pragma unroll
  for (int i=0;i<4;i++){
    #pragma unroll
    for (int j=0;j<4;j++){
      #pragma unroll
      for (int r=0;r<4;r++){
        const int m = m0 + wr + i*16 + quad*4 + r;
        const int n = n0 + wc + j*16 + lr;
        float t = acc[i][j][r];
        if (EPI == 0){
          const int proj = n >> 10;        // 0=q,1=k,2=v (block-uniform)
          const int s = m >> 2, b = m & 3, h = (n >> 6) & 15, kk = n & 63;
          C[(size_t)proj*8388608 + (((size_t)(b*16 + h)) * S_ + s) * 64 + kk] = f2bf(t);
        } else {
          const size_t off = (size_t)m * Ncols + n;
          if (EPI == 1) t += ((const float*)res)[off];
          if (EPI == 2) t = fmaxf(t + bias[n], 0.f);
          if (EPI == 3) t += bias[n] + bf2f(((const unsigned short*)res)[off]);
          C[off] = f2bf(t);
        }
      }
    }
  }
}

// ---------------------------------------------------------------------------
// V transpose: v head-major [bh][s][64] -> vT [bh][d][S]. Coalesced writes.
// grid (S/64, 64), 256 thr.
// ---------------------------------------------------------------------------
__global__ __launch_bounds__(256) void vtrans(const unsigned short* __restrict__ v,
                                              unsigned short* __restrict__ vT){
  const int tid = threadIdx.x;
  const int wave = tid >> 6, ln = tid & 63;
  const int bh = blockIdx.y;
  const int s  = blockIdx.x * 64 + ln;
  const int d0 = wave * 16;
  unsigned short tmp[16];
  const unsigned short* src = v + ((size_t)bh * S_ + s) * 64 + d0;
  *(uint4*)&tmp[0] = ((const uint4*)src)[0];
  *(uint4*)&tmp[8] = ((const uint4*)src)[1];
  unsigned short* dst = vT + (size_t)bh * 64 * S_ + s;
  #pragma unroll
  for (int e = 0; e < 16; e++)
    dst[(size_t)(d0 + e) * S_] = tmp[e];
}

// ---------------------------------------------------------------------------
// Fused flash attention v5 = R2-proven v3 with two changes:
//  (1) V frags read DIRECTLY from global vT (no VTs LDS tile): same 32 vf
//      VGPRs, loads issued right after the barrier, ~400 cyc before PV use
//      (QK MFMA + softmax cover the latency); L2 serves the 16 same-bh
//      blocks. LDS 50 KB -> 34 KB -> 4 blocks/CU (was 3): +33% waves/SIMD
//      for the stall-bound 57%-combined-busy pipes.
//  (2) lsum computed by MFMA ones-column: accL[qb] += mfma(ap, ones) (4
//      MFMA/iter on the 19%-busy matrix pipe) replaces 32 VALU adds/iter +
//      the final shfl reduce; denominator now sums the same bf16 P as the
//      numerator (consistent numerics).
// Rest identical: Ks XOR-swizzled dbuf staging, 1 barrier/iter, exp2
// softmax with pre-scaled mask, cvt_pk Ps stores, setprio (T5).
// ---------------------------------------------------------------------------
__global__ __launch_bounds__(256) void fattn(
    const unsigned short* __restrict__ qg, const unsigned short* __restrict__ kg,
    const unsigned short* __restrict__ vT, const float* __restrict__ mb,
    unsigned short* __restrict__ av)
{
  __shared__ unsigned short Ks[2][4096];    // [t][d] 64x64, XOR-swizzled cols
  __shared__ unsigned short Ps[4*32*72];    // per-wave 32 q-rows x 64 t, stride 72
  const int tid  = threadIdx.x;
  const int wave = tid >> 6, ln = tid & 63;
  const int lr   = ln & 15, quad = ln >> 4;
  const int bh   = blockIdx.y;
  const int b    = bh >> 4, h = bh & 15;
  const int s0   = blockIdx.x * 128;
  const size_t base  = (size_t)bh * S_ * 64;    // q/k head-major
  const size_t tbase = (size_t)bh * 64 * S_;    // vT
  const int qw = s0 + wave*32;

  // Q A-frags direct from global: [m=lr][k=quad*8+j]
  bfrag aq[2][2];
  #pragma unroll
  for (int qb=0;qb<2;qb++)
    #pragma unroll
    for (int hh=0;hh<2;hh++)
      aq[qb][hh] = *(const bfrag*)(qg + base + (size_t)(qw + qb*16 + lr)*64 + hh*32 + quad*8);

  const f4 zero = {0.f, 0.f, 0.f, 0.f};
  const bfrag vones = { (short)0x3F80, (short)0x3F80, (short)0x3F80, (short)0x3F80,
                        (short)0x3F80, (short)0x3F80, (short)0x3F80, (short)0x3F80 };
  f4 acc[2][4];   // [qb][nb]
  f4 accL[2];     // row-sum accumulator (ones-column PV)
  #pragma unroll
  for (int qb=0;qb<2;qb++){
    #pragma unroll
    for (int nb=0;nb<4;nb++) acc[qb][nb] = zero;
    accL[qb] = zero;
  }

  // staging: wave w fills rows [w*16, w*16+16) of the 64-row K tile.
  // dest is linear (gload_lds: base + lane*16B); SOURCE col is
  // inverse-swizzled so that physical col c16 holds logical c16^(row&7).
  const int strow = wave*16 + (ln >> 3);            // +0 / +8 per inst
  const int scz   = ((ln & 7) ^ (ln >> 3)) * 8;     // swizzled col (shorts)
  const int rxor  = lr & 7;                          // read-side xor (row&7)

  unsigned short* const psw = &Ps[wave*2304];

  // per-row mask base pointers (pre-scaled mask, fp32)
  const float* mrow[2][4];
  #pragma unroll
  for (int qb=0;qb<2;qb++)
    #pragma unroll
    for (int r=0;r<4;r++)
      mrow[qb][r] = mb + (size_t)(qw + qb*16 + quad*4 + r) * S_ + lr;

  // per-lane V source base: row d = nb*16+lr of vT (16B aligned)
  const unsigned short* vsrc = vT + tbase + (size_t)lr * S_ + quad*8;

  auto stage = [&](int bufn, int t0n){
    unsigned short* kd = &Ks[bufn][(wave*16)*64];
    gload16(kg + base + (size_t)(t0n + strow    )*64 + scz, kd);
    gload16(kg + base + (size_t)(t0n + strow + 8)*64 + scz, kd + 512);
  };

  stage(0, 0);
  int cur = 0;

  for (int t0 = 0; t0 < S_; t0 += 64){
    __syncthreads();   // drains prev stage (had full compute phase to land)

    // V frags direct from global (use is ~QK+softmax later: latency covered)
    bfrag vf[4][2];
    #pragma unroll
    for (int nb=0;nb<4;nb++)
      #pragma unroll
      for (int hh=0;hh<2;hh++)
        vf[nb][hh] = *(const bfrag*)(vsrc + (size_t)(nb*16) * S_ + t0 + hh*32);

    // mask prefetch for current tile
    float mreg[2][4][4];
    #pragma unroll
    for (int qb=0;qb<2;qb++)
      #pragma unroll
      for (int r=0;r<4;r++)
        #pragma unroll
        for (int tb=0;tb<4;tb++)
          mreg[qb][r][tb] = mrow[qb][r][t0 + tb*16];

    if (t0 + 64 < S_) stage(cur ^ 1, t0 + 64);

    const unsigned short* Kc = Ks[cur];

    // K B-frags (shared across qb), swizzled cols
    bfrag kf[4][2];
    #pragma unroll
    for (int tb=0;tb<4;tb++)
      #pragma unroll
      for (int hh=0;hh<2;hh++)
        kf[tb][hh] = *(const bfrag*)&Kc[(tb*16 + lr)*64 + (((hh*4 + quad) ^ rxor))*8];

    // scores -> exp2 -> Ps (no-max softmax)
    #pragma unroll
    for (int qb=0;qb<2;qb++){
      f4 sc[4];
      __builtin_amdgcn_s_setprio(1);
      #pragma unroll
      for (int tb=0;tb<4;tb++){
        f4 t = zero;
        t = __builtin_amdgcn_mfma_f32_16x16x32_bf16(aq[qb][0], kf[tb][0], t, 0, 0, 0);
        t = __builtin_amdgcn_mfma_f32_16x16x32_bf16(aq[qb][1], kf[tb][1], t, 0, 0, 0);
        sc[tb] = t;
      }
      __builtin_amdgcn_s_setprio(0);
      #pragma unroll
      for (int tb=0;tb<4;tb++){
        float p0 = __builtin_amdgcn_exp2f(fmaf(sc[tb][0], 0.18033688f, mreg[qb][0][tb]));
        float p1 = __builtin_amdgcn_exp2f(fmaf(sc[tb][1], 0.18033688f, mreg[qb][1][tb]));
        float p2 = __builtin_amdgcn_exp2f(fmaf(sc[tb][2], 0.18033688f, mreg[qb][2][tb]));
        float p3 = __builtin_amdgcn_exp2f(fmaf(sc[tb][3], 0.18033688f, mreg[qb][3][tb]));
        unsigned int pkA, pkB;
        asm("v_cvt_pk_bf16_f32 %0, %1, %2" : "=v"(pkA) : "v"(p0), "v"(p1));
        asm("v_cvt_pk_bf16_f32 %0, %1, %2" : "=v"(pkB) : "v"(p2), "v"(p3));
        unsigned short* pp = &psw[(qb*16 + quad*4)*72 + tb*16 + lr];
        pp[0]   = (unsigned short)pkA;
        pp[72]  = (unsigned short)(pkA >> 16);
        pp[144] = (unsigned short)pkB;
        pp[216] = (unsigned short)(pkB >> 16);
      }
    }

    // PV: acc[qb][nb] += P V ; accL[qb] += P ones (row-sum in matrix pipe)
    __builtin_amdgcn_s_setprio(1);
    #pragma unroll
    for (int qb=0;qb<2;qb++){
      bfrag ap0 = *(const bfrag*)&psw[(qb*16 + lr)*72 + quad*8];
      bfrag ap1 = *(const bfrag*)&psw[(qb*16 + lr)*72 + 32 + quad*8];
      #pragma unroll
      for (int nb=0;nb<4;nb++){
        acc[qb][nb] = __builtin_amdgcn_mfma_f32_16x16x32_bf16(ap0, vf[nb][0], acc[qb][nb], 0, 0, 0);
        acc[qb][nb] = __builtin_amdgcn_mfma_f32_16x16x32_bf16(ap1, vf[nb][1], acc[qb][nb], 0, 0, 0);
      }
      accL[qb] = __builtin_amdgcn_mfma_f32_16x16x32_bf16(ap0, vones, accL[qb], 0, 0, 0);
      accL[qb] = __builtin_amdgcn_mfma_f32_16x16x32_bf16(ap1, vones, accL[qb], 0, 0, 0);
    }
    __builtin_amdgcn_s_setprio(0);
    cur ^= 1;
  }

  // normalize + write out (row-major av); accL[qb][r] is the full row sum
  #pragma unroll
  for (int qb=0;qb<2;qb++)
    #pragma unroll
    for (int r=0;r<4;r++){
      const float inv = 1.f / accL[qb][r];
      const int qrow = qw + qb*16 + quad*4 + r;
      #pragma unroll
      for (int nb=0;nb<4;nb++)
        av[((size_t)qrow * B_ + b) * HK_ + h*64 + nb*16 + lr] = f2bf(acc[qb][nb][r] * inv);
    }
}

// ---------------------------------------------------------------------------
// LayerNorm over D=1024 (R7-proven). bf16 in, fp32 g/b, bf16 or fp32 out.
// ---------------------------------------------------------------------------
template<int OUTF32>
__global__ __launch_bounds__(256) void lnk(
    const unsigned short* __restrict__ pre, const float* __restrict__ g,
    const float* __restrict__ be, void* __restrict__ out)
{
  __shared__ float red[256];
  const int row = blockIdx.x;
  const int tid = threadIdx.x;
  const unsigned short* p = pre + (size_t)row * D_;
  uint2 raw = *(const uint2*)(p + tid*4);
  float x[4] = { bf2f(raw.x & 0xffffu), bf2f(raw.x >> 16),
                 bf2f(raw.y & 0xffffu), bf2f(raw.y >> 16) };
  red[tid] = x[0] + x[1] + x[2] + x[3];
  __syncthreads();
  for (int q = 128; q > 0; q >>= 1){
    if (tid < q) red[tid] += red[tid + q];
    __syncthreads();
  }
  const float mu = red[0] * (1.f / (float)D_);
  __syncthreads();
  float d0 = x[0]-mu, d1 = x[1]-mu, d2 = x[2]-mu, d3 = x[3]-mu;
  red[tid] = d0*d0 + d1*d1 + d2*d2 + d3*d3;
  __syncthreads();
  for (int q = 128; q > 0; q >>= 1){
    if (tid < q) red[tid] += red[tid + q];
    __syncthreads();
  }
  const float rstd = rsqrtf(red[0] * (1.f / (float)D_) + 1e-5f);
  const int c = tid * 4;
  #pragma unroll
  for (int j=0;j<4;j++){
    float y = (x[j] - mu) * rstd * g[c + j] + be[c + j];
    if (OUTF32) ((float*)out)[(size_t)row * D_ + c + j] = y;
    else ((unsigned short*)out)[(size_t)row * D_ + c + j] = f2bf(y);
  }
}

// ---------------------------------------------------------------------------
// ws layout (ushort elems; peak 62,914,560 = 120 MiB, same as R7):
//  xb @0 | wqb @8388608 | wkb @9437184 | wvb @10485760 | wcb @11534336
//  q @12582912 | k @20971520 | v @29360128 | w1wb @37748736 | w2wb @41943040
//  u @46137344 | z @54525952. vT reuses z slot (free until last gemm);
//  av -> xb slot; t1 -> q slot; h1 @0. mb (scaled mask, fp32 16MB) reuses
//  u slot (free until LN1, i.e. until after fattn).
// wqb/wkb/wvb contiguous -> merged 3072-row weight for one QKV GEMM;
// q/k/v contiguous at stride 8388608 -> proj offset in mgemm<0> epilogue.
// ---------------------------------------------------------------------------
extern "C" void kernel_launch(void* const* d_in, const int* in_sizes, int n_in,
                              void* d_out, int out_size, void* d_ws, size_t ws_size,
                              hipStream_t stream) {
  const float* x    = (const float*)d_in[0];
  const float* mask = (const float*)d_in[1];
  const float* wq   = (const float*)d_in[2];
  const float* wk   = (const float*)d_in[3];
  const float* wv   = (const float*)d_in[4];
  const float* wc   = (const float*)d_in[5];
  const float* w1w  = (const float*)d_in[6];
  const float* w1b  = (const float*)d_in[7];
  const float* w2w  = (const float*)d_in[8];
  const float* w2b  = (const float*)d_in[9];
  const float* g1   = (const float*)d_in[10];
  const float* b1   = (const float*)d_in[11];
  const float* g2   = (const float*)d_in[12];
  const float* b2   = (const float*)d_in[13];

  unsigned short* ws = (unsigned short*)d_ws;
  unsigned short* xb   = ws + 0;
  unsigned short* wqb  = ws + 8388608;
  unsigned short* wkb  = ws + 9437184;
  unsigned short* wvb  = ws + 10485760;
  unsigned short* wcb  = ws + 11534336;
  unsigned short* q    = ws + 12582912;
  unsigned short* k    = ws + 20971520;
  unsigned short* v    = ws + 29360128;
  unsigned short* w1wb = ws + 37748736;
  unsigned short* w2wb = ws + 41943040;
  unsigned short* u    = ws + 46137344;
  unsigned short* z    = ws + 54525952;
  unsigned short* vT   = z;               // free until final gemm
  unsigned short* avb  = ws + 0;          // xb dead after QKV
  unsigned short* t1   = ws + 12582912;   // q slot
  unsigned short* h1   = ws + 0;          // over dead av region
  float*          mb   = (float*)(ws + 46137344);  // u slot, 4M floats

  // casts + mask pre-scale
  castk<<<8192, 256, 0, stream>>>(x,   xb);
  castw4<<<4096, 256, 0, stream>>>(wq, wk, wv, wc, wqb);
  castk<<<4096, 256, 0, stream>>>(w1w, w1wb);
  castk<<<4096, 256, 0, stream>>>(w2w, w2wb);
  mscale<<<4096, 256, 0, stream>>>(mask, mb);

  // merged QKV projection -> head-major bf16 (one dispatch, 1536 blocks)
  mgemm<0><<<dim3(24, 64), 256, 0, stream>>>(xb, wqb, nullptr, nullptr, q, D_, 3072);

  // V transpose, then fused attention -> av (row-major)
  vtrans<<<dim3(S_/64, 64), 256, 0, stream>>>(v, vT);
  fattn<<<dim3(S_/128, B_*H_), 256, 0, stream>>>(q, k, vT, mb, avb);

  // t1 = av @ wc^T + x ; u = LN1(t1)
  mgemm<1><<<dim3(8, 64), 256, 0, stream>>>(avb, wcb, nullptr, x, t1, HK_, D_);
  lnk<0><<<dim3(N_), 256, 0, stream>>>(t1, g1, b1, u);

  // h1 = relu(u @ w1^T + b1)
  mgemm<2><<<dim3(32, 64), 256, 0, stream>>>(u, w1wb, w1b, nullptr, h1, D_, M_);

  // z = h1 @ w2^T + b2 + u ; out = LN2(z) -> fp32
  mgemm<3><<<dim3(8, 64), 256, 0, stream>>>(h1, w2wb, w2b, u, z, M_, D_);
  lnk<1><<<dim3(N_), 256, 0, stream>>>(z, g2, b2, d_out);
}

// Round 9
// 573.997 us; speedup vs baseline: 1.1313x; 1.1313x over previous
//
#include <hip/hip_runtime.h>
#include <math.h>

#define H_  16
#define K_  64
#define D_  1024
#define M_  4096
#define S_  2048
#define B_  4
#define N_  8192      // S*B
#define HK_ 1024      // H*K

// Externals (inputs + output) fp32. ws intermediates bf16.
typedef __attribute__((ext_vector_type(8))) short bfrag;   // 8 bf16 = 4 VGPRs (MFMA A/B frag)
typedef __attribute__((ext_vector_type(4))) float f4;      // MFMA C/D frag

typedef __attribute__((address_space(1))) const void g_void;
typedef __attribute__((address_space(3))) void s_void;

__device__ __forceinline__ float bf2f(unsigned short u){
  union { unsigned int i; float f; } x; x.i = ((unsigned int)u) << 16; return x.f;
}
__device__ __forceinline__ unsigned short f2bf(float f){
  unsigned int u = __float_as_uint(f);
  return (unsigned short)((u + 0x7fffu + ((u >> 16) & 1u)) >> 16);   // RNE
}
__device__ __forceinline__ unsigned int pack2(float a, float b){
  return (unsigned int)f2bf(a) | ((unsigned int)f2bf(b) << 16);
}
// async global->LDS, 16B per lane, dest = wave-uniform base + lane*16
__device__ __forceinline__ void gload16(const void* g, void* l){
  __builtin_amdgcn_global_load_lds((g_void*)g, (s_void*)l, 16, 0, 0);
}

// ---------------------------------------------------------------------------
// fp32 -> bf16 cast, 4 elems/thread
// ---------------------------------------------------------------------------
__global__ __launch_bounds__(256) void castk(const float* __restrict__ in,
                                             unsigned short* __restrict__ out){
  int i = (blockIdx.x * 256 + threadIdx.x) * 4;
  float4 v = *(const float4*)(in + i);
  *(uint2*)(out + i) = make_uint2(pack2(v.x, v.y), pack2(v.z, v.w));
}

// ---------------------------------------------------------------------------
// merged cast of 4x 1Mx-elem weights (wq,wk,wv,wc) -> contiguous bf16.
// grid 4096, 1024 blocks per input.
// ---------------------------------------------------------------------------
__global__ __launch_bounds__(256) void castw4(
    const float* __restrict__ a, const float* __restrict__ b,
    const float* __restrict__ c, const float* __restrict__ d,
    unsigned short* __restrict__ out){
  const int blk = blockIdx.x;
  const int seg = blk >> 10;
  const float* src = (seg == 0) ? a : (seg == 1) ? b : (seg == 2) ? c : d;
  const int rel = ((blk & 1023) * 256 + threadIdx.x) * 4;
  float4 v = *(const float4*)(src + rel);
  *(uint2*)(out + (size_t)seg * 1048576 + rel) = make_uint2(pack2(v.x, v.y), pack2(v.z, v.w));
}

// ---------------------------------------------------------------------------
// mask * log2(e), fp32 -> fp32 (lets fattn use exp2 directly: 1 fma + 1 exp)
// ---------------------------------------------------------------------------
__global__ __launch_bounds__(256) void mscale(const float* __restrict__ in,
                                              float* __restrict__ out){
  int i = (blockIdx.x * 256 + threadIdx.x) * 4;
  float4 v = *(const float4*)(in + i);
  const float c = 1.44269504f;
  v.x *= c; v.y *= c; v.z *= c; v.w *= c;
  *(float4*)(out + i) = v;
}

// ---------------------------------------------------------------------------
// MFMA GEMM v5 (R7-proven): 128x128 tile, BK=32, 4 waves, triple-buffered
// counted-vmcnt + XCD-chunked block swizzle (T1). LDS 48 KB.
// EPI: 0 = merged-QKV head-major out (proj = n>>10); 1 = +fp32 res;
// 2 = +bias relu; 3 = +bias +bf16 res.
// ---------------------------------------------------------------------------
template<int EPI>
__global__ __launch_bounds__(256) void mgemm(
    const unsigned short* __restrict__ A, const unsigned short* __restrict__ W,
    const float* __restrict__ bias, const void* __restrict__ res,
    unsigned short* __restrict__ C, int Kdim, int Ncols)
{
  __shared__ unsigned short sA[3][4096];   // 128 rows x 32 k, triple-buffered
  __shared__ unsigned short sB[3][4096];
  const int tid  = threadIdx.x;
  const int wave = tid >> 6, ln = tid & 63;
  const int lr   = ln & 15, quad = ln >> 4;

  // XCD-chunked swizzle (T1): hardware assigns bid -> XCD bid%8; remap so
  // XCD k processes logical tiles [k*cpx, (k+1)*cpx) in x-fastest order.
  const int nwg = gridDim.x * gridDim.y;
  const int bid = blockIdx.x + gridDim.x * blockIdx.y;
  const int cpx = nwg >> 3;                // nwg % 8 == 0 for all our grids
  const int swz = (bid & 7) * cpx + (bid >> 3);
  const int bx  = swz % gridDim.x, by = swz / gridDim.x;

  const int m0   = by * 128, n0 = bx * 128;
  const int wr   = (wave >> 1) * 64, wc = (wave & 1) * 64;
  const int segr = ln >> 2, segc = (ln & 3) * 8;
  const int sg   = wave * 2;

  const unsigned short* A0 = A + (size_t)(m0 + sg*16      + segr) * Kdim + segc;
  const unsigned short* A1 = A + (size_t)(m0 + sg*16 + 16 + segr) * Kdim + segc;
  const unsigned short* W0 = W + (size_t)(n0 + sg*16      + segr) * Kdim + segc;
  const unsigned short* W1 = W + (size_t)(n0 + sg*16 + 16 + segr) * Kdim + segc;

  const f4 zero = {0.f, 0.f, 0.f, 0.f};
  f4 acc[4][4];
  #pragma unroll
  for (int i=0;i<4;i++)
    #pragma unroll
    for (int j=0;j<4;j++) acc[i][j] = zero;

  auto stage = [&](int buf, int k0){
    gload16(A0 + k0, &sA[buf][sg*512]);
    gload16(A1 + k0, &sA[buf][sg*512 + 512]);
    gload16(W0 + k0, &sB[buf][sg*512]);
    gload16(W1 + k0, &sB[buf][sg*512 + 512]);
  };

  stage(0, 0);
  if (32 < Kdim) stage(1, 32);
  int cur = 0;

  for (int k0 = 0; k0 < Kdim; k0 += 32){
    // need chunk k0 landed; chunk k0+32 (4 loads) may stay in flight
    if (k0 + 32 < Kdim) asm volatile("s_waitcnt vmcnt(4)" ::: "memory");
    else                asm volatile("s_waitcnt vmcnt(0)" ::: "memory");
    __builtin_amdgcn_s_barrier();
    int nxt = cur + 2; if (nxt >= 3) nxt -= 3;
    if (k0 + 64 < Kdim) stage(nxt, k0 + 64);   // 2 compute phases to land

    bfrag af[4], bf[4];
    #pragma unroll
    for (int i=0;i<4;i++) af[i] = *(const bfrag*)&sA[cur][(wr + i*16 + lr)*32 + quad*8];
    #pragma unroll
    for (int j=0;j<4;j++) bf[j] = *(const bfrag*)&sB[cur][(wc + j*16 + lr)*32 + quad*8];
    #pragma unroll
    for (int i=0;i<4;i++)
      #pragma unroll
      for (int j=0;j<4;j++)
        acc[i][j] = __builtin_amdgcn_mfma_f32_16x16x32_bf16(af[i], bf[j], acc[i][j], 0, 0, 0);
    cur = (cur + 1 == 3) ? 0 : cur + 1;
  }

  #pragma unroll
  for (int i=0;i<4;i++){
    #pragma unroll
    for (int j=0;j<4;j++){
      #pragma unroll
      for (int r=0;r<4;r++){
        const int m = m0 + wr + i*16 + quad*4 + r;
        const int n = n0 + wc + j*16 + lr;
        float t = acc[i][j][r];
        if (EPI == 0){
          const int proj = n >> 10;        // 0=q,1=k,2=v (block-uniform)
          const int s = m >> 2, b = m & 3, h = (n >> 6) & 15, kk = n & 63;
          C[(size_t)proj*8388608 + (((size_t)(b*16 + h)) * S_ + s) * 64 + kk] = f2bf(t);
        } else {
          const size_t off = (size_t)m * Ncols + n;
          if (EPI == 1) t += ((const float*)res)[off];
          if (EPI == 2) t = fmaxf(t + bias[n], 0.f);
          if (EPI == 3) t += bias[n] + bf2f(((const unsigned short*)res)[off]);
          C[off] = f2bf(t);
        }
      }
    }
  }
}

// ---------------------------------------------------------------------------
// V transpose: v head-major [bh][s][64] -> vT [bh][d][S]. Coalesced writes.
// grid (S/64, 64), 256 thr.
// ---------------------------------------------------------------------------
__global__ __launch_bounds__(256) void vtrans(const unsigned short* __restrict__ v,
                                              unsigned short* __restrict__ vT){
  const int tid = threadIdx.x;
  const int wave = tid >> 6, ln = tid & 63;
  const int bh = blockIdx.y;
  const int s  = blockIdx.x * 64 + ln;
  const int d0 = wave * 16;
  unsigned short tmp[16];
  const unsigned short* src = v + ((size_t)bh * S_ + s) * 64 + d0;
  *(uint4*)&tmp[0] = ((const uint4*)src)[0];
  *(uint4*)&tmp[8] = ((const uint4*)src)[1];
  unsigned short* dst = vT + (size_t)bh * 64 * S_ + s;
  #pragma unroll
  for (int e = 0; e < 16; e++)
    dst[(size_t)(d0 + e) * S_] = tmp[e];
}

// ---------------------------------------------------------------------------
// Fused flash attention v6 = R7-proven v3 (VTs LDS staging RESTORED after the
// R8 V-direct regression: global vf reads have 4KB lane stride = 64-way
// scatter; coalesced gload16 staging amortizes the transpose once) with ONE
// retained R8 change: lsum via ones-column MFMA — accL[qb] += mfma(ap, ones)
// (4 MFMA/iter on the ~20%-busy matrix pipe) replaces 32 VALU adds/iter +
// the final 4-step shfl reduce on the ~37%-busy VALU pipe. Denominator now
// sums the same bf16 P as the numerator (consistent numerics).
// Rest identical to R7: Ks/VTs XOR-swizzled dbuf, 1 barrier/iter, exp2
// softmax with pre-scaled mask, cvt_pk Ps stores, setprio (T5). LDS 50 KiB.
// ---------------------------------------------------------------------------
__global__ __launch_bounds__(256) void fattn(
    const unsigned short* __restrict__ qg, const unsigned short* __restrict__ kg,
    const unsigned short* __restrict__ vT, const float* __restrict__ mb,
    unsigned short* __restrict__ av)
{
  __shared__ unsigned short Ks[2][4096];    // [t][d] 64x64, XOR-swizzled cols
  __shared__ unsigned short VTs[2][4096];   // [d][t] 64x64, XOR-swizzled cols
  __shared__ unsigned short Ps[4*32*72];    // per-wave 32 q-rows x 64 t, stride 72
  const int tid  = threadIdx.x;
  const int wave = tid >> 6, ln = tid & 63;
  const int lr   = ln & 15, quad = ln >> 4;
  const int bh   = blockIdx.y;
  const int b    = bh >> 4, h = bh & 15;
  const int s0   = blockIdx.x * 128;
  const size_t base  = (size_t)bh * S_ * 64;    // q/k head-major
  const size_t tbase = (size_t)bh * 64 * S_;    // vT
  const int qw = s0 + wave*32;

  // Q A-frags direct from global: [m=lr][k=quad*8+j]
  bfrag aq[2][2];
  #pragma unroll
  for (int qb=0;qb<2;qb++)
    #pragma unroll
    for (int hh=0;hh<2;hh++)
      aq[qb][hh] = *(const bfrag*)(qg + base + (size_t)(qw + qb*16 + lr)*64 + hh*32 + quad*8);

  const f4 zero = {0.f, 0.f, 0.f, 0.f};
  const bfrag vones = { (short)0x3F80, (short)0x3F80, (short)0x3F80, (short)0x3F80,
                        (short)0x3F80, (short)0x3F80, (short)0x3F80, (short)0x3F80 };
  f4 acc[2][4];   // [qb][nb]
  f4 accL[2];     // row-sum accumulator (ones-column PV)
  #pragma unroll
  for (int qb=0;qb<2;qb++){
    #pragma unroll
    for (int nb=0;nb<4;nb++) acc[qb][nb] = zero;
    accL[qb] = zero;
  }

  // staging: wave w fills rows [w*16, w*16+16) of each 64-row tile.
  // dest is linear (gload_lds: base + lane*16B); SOURCE col is
  // inverse-swizzled so that physical col c16 holds logical c16^(row&7).
  const int strow = wave*16 + (ln >> 3);            // +0 / +8 per inst
  const int scz   = ((ln & 7) ^ (ln >> 3)) * 8;     // swizzled col (shorts)
  const int rxor  = lr & 7;                          // read-side xor (row&7)

  unsigned short* const psw = &Ps[wave*2304];

  // per-row mask base pointers (pre-scaled mask, fp32)
  const float* mrow[2][4];
  #pragma unroll
  for (int qb=0;qb<2;qb++)
    #pragma unroll
    for (int r=0;r<4;r++)
      mrow[qb][r] = mb + (size_t)(qw + qb*16 + quad*4 + r) * S_ + lr;

  auto stage = [&](int bufn, int t0n){
    unsigned short* kd = &Ks[bufn][(wave*16)*64];
    unsigned short* vd = &VTs[bufn][(wave*16)*64];
    gload16(kg + base  + (size_t)(t0n + strow    )*64 + scz, kd);
    gload16(kg + base  + (size_t)(t0n + strow + 8)*64 + scz, kd + 512);
    gload16(vT + tbase + (size_t)(strow    )*S_ + t0n + scz, vd);
    gload16(vT + tbase + (size_t)(strow + 8)*S_ + t0n + scz, vd + 512);
  };

  stage(0, 0);
  int cur = 0;

  for (int t0 = 0; t0 < S_; t0 += 64){
    __syncthreads();   // drains prev stage (had full compute phase to land)

    // mask prefetch for current tile (issued BEFORE next stage so the
    // softmax wait is vmcnt(4), leaving the stage loads in flight)
    float mreg[2][4][4];
    #pragma unroll
    for (int qb=0;qb<2;qb++)
      #pragma unroll
      for (int r=0;r<4;r++)
        #pragma unroll
        for (int tb=0;tb<4;tb++)
          mreg[qb][r][tb] = mrow[qb][r][t0 + tb*16];

    if (t0 + 64 < S_) stage(cur ^ 1, t0 + 64);

    const unsigned short* Kc = Ks[cur];
    const unsigned short* Vc = VTs[cur];

    // K B-frags (shared across qb), swizzled cols
    bfrag kf[4][2];
    #pragma unroll
    for (int tb=0;tb<4;tb++)
      #pragma unroll
      for (int hh=0;hh<2;hh++)
        kf[tb][hh] = *(const bfrag*)&Kc[(tb*16 + lr)*64 + (((hh*4 + quad) ^ rxor))*8];

    // V B-frags, swizzled cols
    bfrag vf[4][2];
    #pragma unroll
    for (int nb=0;nb<4;nb++)
      #pragma unroll
      for (int hh=0;hh<2;hh++)
        vf[nb][hh] = *(const bfrag*)&Vc[(nb*16 + lr)*64 + (((hh*4 + quad) ^ rxor))*8];

    // scores -> exp2 -> Ps (no-max softmax)
    #pragma unroll
    for (int qb=0;qb<2;qb++){
      f4 sc[4];
      __builtin_amdgcn_s_setprio(1);
      #pragma unroll
      for (int tb=0;tb<4;tb++){
        f4 t = zero;
        t = __builtin_amdgcn_mfma_f32_16x16x32_bf16(aq[qb][0], kf[tb][0], t, 0, 0, 0);
        t = __builtin_amdgcn_mfma_f32_16x16x32_bf16(aq[qb][1], kf[tb][1], t, 0, 0, 0);
        sc[tb] = t;
      }
      __builtin_amdgcn_s_setprio(0);
      #pragma unroll
      for (int tb=0;tb<4;tb++){
        float p0 = __builtin_amdgcn_exp2f(fmaf(sc[tb][0], 0.18033688f, mreg[qb][0][tb]));
        float p1 = __builtin_amdgcn_exp2f(fmaf(sc[tb][1], 0.18033688f, mreg[qb][1][tb]));
        float p2 = __builtin_amdgcn_exp2f(fmaf(sc[tb][2], 0.18033688f, mreg[qb][2][tb]));
        float p3 = __builtin_amdgcn_exp2f(fmaf(sc[tb][3], 0.18033688f, mreg[qb][3][tb]));
        unsigned int pkA, pkB;
        asm("v_cvt_pk_bf16_f32 %0, %1, %2" : "=v"(pkA) : "v"(p0), "v"(p1));
        asm("v_cvt_pk_bf16_f32 %0, %1, %2" : "=v"(pkB) : "v"(p2), "v"(p3));
        unsigned short* pp = &psw[(qb*16 + quad*4)*72 + tb*16 + lr];
        pp[0]   = (unsigned short)pkA;
        pp[72]  = (unsigned short)(pkA >> 16);
        pp[144] = (unsigned short)pkB;
        pp[216] = (unsigned short)(pkB >> 16);
      }
    }

    // PV: acc[qb][nb] += P V ; accL[qb] += P ones (row-sum on matrix pipe)
    __builtin_amdgcn_s_setprio(1);
    #pragma unroll
    for (int qb=0;qb<2;qb++){
      bfrag ap0 = *(const bfrag*)&psw[(qb*16 + lr)*72 + quad*8];
      bfrag ap1 = *(const bfrag*)&psw[(qb*16 + lr)*72 + 32 + quad*8];
      #pragma unroll
      for (int nb=0;nb<4;nb++){
        acc[qb][nb] = __builtin_amdgcn_mfma_f32_16x16x32_bf16(ap0, vf[nb][0], acc[qb][nb], 0, 0, 0);
        acc[qb][nb] = __builtin_amdgcn_mfma_f32_16x16x32_bf16(ap1, vf[nb][1], acc[qb][nb], 0, 0, 0);
      }
      accL[qb] = __builtin_amdgcn_mfma_f32_16x16x32_bf16(ap0, vones, accL[qb], 0, 0, 0);
      accL[qb] = __builtin_amdgcn_mfma_f32_16x16x32_bf16(ap1, vones, accL[qb], 0, 0, 0);
    }
    __builtin_amdgcn_s_setprio(0);
    cur ^= 1;
  }

  // normalize + write out (row-major av); accL[qb][r] is the full row sum
  #pragma unroll
  for (int qb=0;qb<2;qb++)
    #pragma unroll
    for (int r=0;r<4;r++){
      const float inv = 1.f / accL[qb][r];
      const int qrow = qw + qb*16 + quad*4 + r;
      #pragma unroll
      for (int nb=0;nb<4;nb++)
        av[((size_t)qrow * B_ + b) * HK_ + h*64 + nb*16 + lr] = f2bf(acc[qb][nb][r] * inv);
    }
}

// ---------------------------------------------------------------------------
// LayerNorm over D=1024, v2: SINGLE tree reduction carrying (sum, sumsq)
// simultaneously (var = E[x^2] - mu^2) — halves the __syncthreads count
// (8 steps instead of 16). bf16 in, fp32 g/b, bf16 or fp32 out.
// ---------------------------------------------------------------------------
template<int OUTF32>
__global__ __launch_bounds__(256) void lnk(
    const unsigned short* __restrict__ pre, const float* __restrict__ g,
    const float* __restrict__ be, void* __restrict__ out)
{
  __shared__ float red[256], red2[256];
  const int row = blockIdx.x;
  const int tid = threadIdx.x;
  const unsigned short* p = pre + (size_t)row * D_;
  uint2 raw = *(const uint2*)(p + tid*4);
  float x[4] = { bf2f(raw.x & 0xffffu), bf2f(raw.x >> 16),
                 bf2f(raw.y & 0xffffu), bf2f(raw.y >> 16) };
  red[tid]  = x[0] + x[1] + x[2] + x[3];
  red2[tid] = x[0]*x[0] + x[1]*x[1] + x[2]*x[2] + x[3]*x[3];
  __syncthreads();
  for (int q = 128; q > 0; q >>= 1){
    if (tid < q){ red[tid] += red[tid + q]; red2[tid] += red2[tid + q]; }
    __syncthreads();
  }
  const float mu   = red[0] * (1.f / (float)D_);
  const float var  = red2[0] * (1.f / (float)D_) - mu * mu;
  const float rstd = rsqrtf(var + 1e-5f);
  const int c = tid * 4;
  #pragma unroll
  for (int j=0;j<4;j++){
    float y = (x[j] - mu) * rstd * g[c + j] + be[c + j];
    if (OUTF32) ((float*)out)[(size_t)row * D_ + c + j] = y;
    else ((unsigned short*)out)[(size_t)row * D_ + c + j] = f2bf(y);
  }
}

// ---------------------------------------------------------------------------
// ws layout (ushort elems; peak 62,914,560 = 120 MiB, same as R7):
//  xb @0 | wqb @8388608 | wkb @9437184 | wvb @10485760 | wcb @11534336
//  q @12582912 | k @20971520 | v @29360128 | w1wb @37748736 | w2wb @41943040
//  u @46137344 | z @54525952. vT reuses z slot (free until last gemm);
//  av -> xb slot; t1 -> q slot; h1 @0. mb (scaled mask, fp32 16MB) reuses
//  u slot (free until LN1, i.e. until after fattn).
// wqb/wkb/wvb contiguous -> merged 3072-row weight for one QKV GEMM;
// q/k/v contiguous at stride 8388608 -> proj offset in mgemm<0> epilogue.
// ---------------------------------------------------------------------------
extern "C" void kernel_launch(void* const* d_in, const int* in_sizes, int n_in,
                              void* d_out, int out_size, void* d_ws, size_t ws_size,
                              hipStream_t stream) {
  const float* x    = (const float*)d_in[0];
  const float* mask = (const float*)d_in[1];
  const float* wq   = (const float*)d_in[2];
  const float* wk   = (const float*)d_in[3];
  const float* wv   = (const float*)d_in[4];
  const float* wc   = (const float*)d_in[5];
  const float* w1w  = (const float*)d_in[6];
  const float* w1b  = (const float*)d_in[7];
  const float* w2w  = (const float*)d_in[8];
  const float* w2b  = (const float*)d_in[9];
  const float* g1   = (const float*)d_in[10];
  const float* b1   = (const float*)d_in[11];
  const float* g2   = (const float*)d_in[12];
  const float* b2   = (const float*)d_in[13];

  unsigned short* ws = (unsigned short*)d_ws;
  unsigned short* xb   = ws + 0;
  unsigned short* wqb  = ws + 8388608;
  unsigned short* wkb  = ws + 9437184;
  unsigned short* wvb  = ws + 10485760;
  unsigned short* wcb  = ws + 11534336;
  unsigned short* q    = ws + 12582912;
  unsigned short* k    = ws + 20971520;
  unsigned short* v    = ws + 29360128;
  unsigned short* w1wb = ws + 37748736;
  unsigned short* w2wb = ws + 41943040;
  unsigned short* u    = ws + 46137344;
  unsigned short* z    = ws + 54525952;
  unsigned short* vT   = z;               // free until final gemm
  unsigned short* avb  = ws + 0;          // xb dead after QKV
  unsigned short* t1   = ws + 12582912;   // q slot
  unsigned short* h1   = ws + 0;          // over dead av region
  float*          mb   = (float*)(ws + 46137344);  // u slot, 4M floats

  // casts + mask pre-scale
  castk<<<8192, 256, 0, stream>>>(x,   xb);
  castw4<<<4096, 256, 0, stream>>>(wq, wk, wv, wc, wqb);
  castk<<<4096, 256, 0, stream>>>(w1w, w1wb);
  castk<<<4096, 256, 0, stream>>>(w2w, w2wb);
  mscale<<<4096, 256, 0, stream>>>(mask, mb);

  // merged QKV projection -> head-major bf16 (one dispatch, 1536 blocks)
  mgemm<0><<<dim3(24, 64), 256, 0, stream>>>(xb, wqb, nullptr, nullptr, q, D_, 3072);

  // V transpose, then fused attention -> av (row-major)
  vtrans<<<dim3(S_/64, 64), 256, 0, stream>>>(v, vT);
  fattn<<<dim3(S_/128, B_*H_), 256, 0, stream>>>(q, k, vT, mb, avb);

  // t1 = av @ wc^T + x ; u = LN1(t1)
  mgemm<1><<<dim3(8, 64), 256, 0, stream>>>(avb, wcb, nullptr, x, t1, HK_, D_);
  lnk<0><<<dim3(N_), 256, 0, stream>>>(t1, g1, b1, u);

  // h1 = relu(u @ w1^T + b1)
  mgemm<2><<<dim3(32, 64), 256, 0, stream>>>(u, w1wb, w1b, nullptr, h1, D_, M_);

  // z = h1 @ w2^T + b2 + u ; out = LN2(z) -> fp32
  mgemm<3><<<dim3(8, 64), 256, 0, stream>>>(h1, w2wb, w2b, u, z, M_, D_);
  lnk<1><<<dim3(N_), 256, 0, stream>>>(z, g2, b2, d_out);
}